// Round 2
// baseline (211.939 us; speedup 1.0000x reference)
//
#include <hip/hip_runtime.h>
#include <math.h>

#define BB 8
#define SS 4096
#define HH 1024
#define KK 2048

// ---------------- Kernel 1: scores = sigmoid(hs @ w) ----------------
// One wave per token (4 waves / 256-thread block). Lane l reads float4
// index (l + 64j): each instruction covers 1 KB contiguous -> coalesced.
// ~48 VGPR -> 8 waves/SIMD; in-flight load volume far exceeds BW*latency,
// so this kernel sits at the HBM read floor (~20-23 us). Unchanged.
__global__ __launch_bounds__(256) void score_kernel(
    const float* __restrict__ hs, const float* __restrict__ w,
    float* __restrict__ scores) {
    const int lane = threadIdx.x & 63;
    const int wv = threadIdx.x >> 6;
    const int token = blockIdx.x * 4 + wv;

    const float4* w4 = (const float4*)w;                       // 4 KB, L1-resident
    const float4* h4 = (const float4*)(hs + (size_t)token * HH);

    double a0 = 0.0, a1 = 0.0, a2 = 0.0, a3 = 0.0;
#pragma unroll
    for (int j = 0; j < 4; ++j) {
        float4 h  = h4[lane + 64 * j];
        float4 wf = w4[lane + 64 * j];
        a0 += (double)h.x * (double)wf.x;
        a1 += (double)h.y * (double)wf.y;
        a2 += (double)h.z * (double)wf.z;
        a3 += (double)h.w * (double)wf.w;
    }
    double acc = (a0 + a1) + (a2 + a3);
#pragma unroll
    for (int off = 1; off < 64; off <<= 1)
        acc += __shfl_xor(acc, off);
    if (lane == 0)
        scores[token] = (float)(1.0 / (1.0 + exp(-acc)));
}

// ---------------- Kernel 2: per-row top-K selection ----------------
// One wave (64 threads) per batch row; whole row (4096 scores) in
// registers as float4[16]. `scores` aliases `maskout` (staged in the
// mask half of the output) -> NO __restrict__; all loads complete before
// any store within the single owning wave.
//
// This round: all wave-wide counts use ballot+popcount instead of
// shuffle trees. Each register slot (m,c) spans 64 distinct values, so
//   count += __popcll(__ballot(u >= mid))
// is one v_cmp (VALU) + s_bcnt1/s_add (SALU, co-issued pipe) per slot,
// and the count lands wave-uniform with ZERO dependent shuffle steps
// (was 6 per bisection iteration + 6-step shfl_up scan per m-group).
// Tie order preserved exactly: element index of f[m] component c on
// lane l is m*256 + l*4 + c; eqs-before = base_m + popcll(eqmask & lt).
__global__ __launch_bounds__(64) void select_kernel(
    const float* scores, float* weights, float* maskout) {
    const int b = blockIdx.x;
    const int lane = threadIdx.x;
    const float4* row4 = (const float4*)(scores + b * SS);

    float4 f[16];
#pragma unroll
    for (int m = 0; m < 16; ++m) f[m] = row4[m * 64 + lane];

    // ---- binary search for threshold (30 iterations, ballot counts) ----
    unsigned lo = 0u, hi = 0x3F800001u;   // (0, 1.0f + 1ulp]: count(>=0)=S>=K, count(>=hi)=0<K
    while (hi - lo > 1u) {
        const unsigned mid = lo + ((hi - lo) >> 1);
        int c = 0;
#pragma unroll
        for (int m = 0; m < 16; ++m) {
            c += __popcll(__ballot(__float_as_uint(f[m].x) >= mid));
            c += __popcll(__ballot(__float_as_uint(f[m].y) >= mid));
            c += __popcll(__ballot(__float_as_uint(f[m].z) >= mid));
            c += __popcll(__ballot(__float_as_uint(f[m].w) >= mid));
        }
        if (c >= KK) lo = mid; else hi = mid;
    }
    const unsigned thr = lo;

    // ---- count strictly-greater (ballot, wave-uniform result) ----
    int cg = 0;
#pragma unroll
    for (int m = 0; m < 16; ++m) {
        cg += __popcll(__ballot(__float_as_uint(f[m].x) > thr));
        cg += __popcll(__ballot(__float_as_uint(f[m].y) > thr));
        cg += __popcll(__ballot(__float_as_uint(f[m].z) > thr));
        cg += __popcll(__ballot(__float_as_uint(f[m].w) > thr));
    }
    const int need = KK - cg;   // ties to accept, lowest index first (>= 1)

    // ---- select + write, index-ordered tie prefix via ballot masks ----
    const unsigned long long lt = (1ULL << lane) - 1ULL;  // lanes strictly below
    float4* w4o = (float4*)(weights + b * SS);
    float4* m4o = (float4*)(maskout + b * SS);
    int base = 0;               // eq-count in groups < m (wave-uniform)
#pragma unroll
    for (int m = 0; m < 16; ++m) {
        const float vals[4] = { f[m].x, f[m].y, f[m].z, f[m].w };
        unsigned u[4];
        unsigned long long eqm[4];
#pragma unroll
        for (int c = 0; c < 4; ++c) {
            u[c] = __float_as_uint(vals[c]);
            eqm[c] = __ballot(u[c] == thr);
        }
        // eqs strictly before (m, lane, 0): group order is (lane, c)
        int r = base;
#pragma unroll
        for (int c = 0; c < 4; ++c) r += __popcll(eqm[c] & lt);
        float wout[4], mout[4];
#pragma unroll
        for (int c = 0; c < 4; ++c) {
            const bool iseq = (u[c] == thr);
            const bool sel = (u[c] > thr) || (iseq && r < need);
            r += iseq ? 1 : 0;
            wout[c] = sel ? vals[c] : 0.0f;
            mout[c] = sel ? 1.0f : 0.0f;
        }
#pragma unroll
        for (int c = 0; c < 4; ++c) base += __popcll(eqm[c]);  // group total (uniform)
        w4o[m * 64 + lane] = make_float4(wout[0], wout[1], wout[2], wout[3]);
        m4o[m * 64 + lane] = make_float4(mout[0], mout[1], mout[2], mout[3]);
    }
}

extern "C" void kernel_launch(void* const* d_in, const int* in_sizes, int n_in,
                              void* d_out, int out_size, void* d_ws, size_t ws_size,
                              hipStream_t stream) {
    const float* hs = (const float*)d_in[0];   // [B,S,H] fp32
    const float* w  = (const float*)d_in[1];   // [H] fp32
    float* out      = (float*)d_out;           // [B*S] weights ++ [B*S] mask
    float* weights  = out;
    float* mask     = out + (size_t)BB * SS;
    float* scores   = mask;                    // stage scores in mask half; d_ws UNUSED

    const int tokens = BB * SS;                // 32768
    score_kernel<<<tokens / 4, 256, 0, stream>>>(hs, w, scores);
    select_kernel<<<BB, 64, 0, stream>>>(scores, out, mask);
}

// Round 5
// 203.855 us; speedup vs baseline: 1.0397x; 1.0397x over previous
//
#include <hip/hip_runtime.h>
#include <math.h>

#define BB 8
#define SS 4096
#define HH 1024
#define KK 2048

typedef float vf4 __attribute__((ext_vector_type(4)));

// ---------------- Kernel 1: scores = sigmoid(hs @ w) ----------------
// 4096 blocks x 256 threads; each wave computes TWO consecutive tokens
// (16384 waves x 2 tokens = 32768). Lane l reads float4 index (l + 64j):
// 1 KB contiguous per instruction, and the wave's two tokens form one
// contiguous 8 KB window -> fully coalesced. hs is streamed once with no
// reuse -> nontemporal loads (skip L2 allocation). w (4 KB) is loaded
// into registers once per wave (normal loads, L1-resident).
//
// Per-token arithmetic is BIT-IDENTICAL to the verified version (same
// j-order double FMAs, same (a0+a1)+(a2+a3) pairing, same xor-tree
// reduce order) -- required so scores match the np reference exactly and
// the top-K set is stable. The two tokens' reduce chains are independent
// and interleave, hiding the ~250-cycle dependent f64 shuffle tree.
__global__ __launch_bounds__(256) void score_kernel(
    const float* __restrict__ hs, const float* __restrict__ w,
    float* __restrict__ scores) {
    const int lane = threadIdx.x & 63;
    const int wv   = threadIdx.x >> 6;
    const int gw   = (int)blockIdx.x * 4 + wv;   // global wave id
    const int t0   = gw * 2;
    const int t1   = t0 + 1;

    const vf4* w4 = (const vf4*)w;
    vf4 wf[4];
#pragma unroll
    for (int j = 0; j < 4; ++j) wf[j] = w4[lane + 64 * j];

    const vf4* hA = (const vf4*)(hs + (size_t)t0 * HH);
    const vf4* hB = (const vf4*)(hs + (size_t)t1 * HH);
    vf4 ha[4], hb[4];
#pragma unroll
    for (int j = 0; j < 4; ++j) {
        ha[j] = __builtin_nontemporal_load(&hA[lane + 64 * j]);
        hb[j] = __builtin_nontemporal_load(&hB[lane + 64 * j]);
    }

    double a0 = 0.0, a1 = 0.0, a2 = 0.0, a3 = 0.0;
    double b0 = 0.0, b1 = 0.0, b2 = 0.0, b3 = 0.0;
#pragma unroll
    for (int j = 0; j < 4; ++j) {
        a0 += (double)ha[j][0] * (double)wf[j][0];
        a1 += (double)ha[j][1] * (double)wf[j][1];
        a2 += (double)ha[j][2] * (double)wf[j][2];
        a3 += (double)ha[j][3] * (double)wf[j][3];
        b0 += (double)hb[j][0] * (double)wf[j][0];
        b1 += (double)hb[j][1] * (double)wf[j][1];
        b2 += (double)hb[j][2] * (double)wf[j][2];
        b3 += (double)hb[j][3] * (double)wf[j][3];
    }
    double accA = (a0 + a1) + (a2 + a3);
    double accB = (b0 + b1) + (b2 + b3);
#pragma unroll
    for (int off = 1; off < 64; off <<= 1) {
        accA += __shfl_xor(accA, off);
        accB += __shfl_xor(accB, off);
    }
    if (lane == 0) {
        scores[t0] = (float)(1.0 / (1.0 + exp(-accA)));
        scores[t1] = (float)(1.0 / (1.0 + exp(-accB)));
    }
}

// ---------------- Kernel 2: per-row top-K selection ----------------
// (Round-2-verified ballot-popcount version, unchanged.)
// One wave per batch row; whole row (4096 scores) in registers as
// float4[16]. `scores` aliases `maskout` (staged in the mask half of the
// output) -> NO __restrict__; all 16 loads complete (they feed the
// binary search) before any store within the single owning wave.
// Element index of f[m] component c on lane l is m*256 + l*4 + c; tie
// prefix is computed in exactly that order via ballot masks.
__global__ __launch_bounds__(64) void select_kernel(
    const float* scores, float* weights, float* maskout) {
    const int b = blockIdx.x;
    const int lane = threadIdx.x;
    const float4* row4 = (const float4*)(scores + b * SS);

    float4 f[16];
#pragma unroll
    for (int m = 0; m < 16; ++m) f[m] = row4[m * 64 + lane];

    // binary search for threshold (30 iterations, ballot counts)
    unsigned lo = 0u, hi = 0x3F800001u;   // (0, 1.0f + 1ulp]
    while (hi - lo > 1u) {
        const unsigned mid = lo + ((hi - lo) >> 1);
        int c = 0;
#pragma unroll
        for (int m = 0; m < 16; ++m) {
            c += __popcll(__ballot(__float_as_uint(f[m].x) >= mid));
            c += __popcll(__ballot(__float_as_uint(f[m].y) >= mid));
            c += __popcll(__ballot(__float_as_uint(f[m].z) >= mid));
            c += __popcll(__ballot(__float_as_uint(f[m].w) >= mid));
        }
        if (c >= KK) lo = mid; else hi = mid;
    }
    const unsigned thr = lo;

    // count strictly-greater (wave-uniform)
    int cg = 0;
#pragma unroll
    for (int m = 0; m < 16; ++m) {
        cg += __popcll(__ballot(__float_as_uint(f[m].x) > thr));
        cg += __popcll(__ballot(__float_as_uint(f[m].y) > thr));
        cg += __popcll(__ballot(__float_as_uint(f[m].z) > thr));
        cg += __popcll(__ballot(__float_as_uint(f[m].w) > thr));
    }
    const int need = KK - cg;   // ties to accept, lowest index first (>= 1)

    // select + write, index-ordered tie prefix via ballot masks
    const unsigned long long lt = (1ULL << lane) - 1ULL;
    float4* w4o = (float4*)(weights + b * SS);
    float4* m4o = (float4*)(maskout + b * SS);
    int base = 0;               // eq-count in groups < m (wave-uniform)
#pragma unroll
    for (int m = 0; m < 16; ++m) {
        const float vals[4] = { f[m].x, f[m].y, f[m].z, f[m].w };
        unsigned u[4];
        unsigned long long eqm[4];
#pragma unroll
        for (int c = 0; c < 4; ++c) {
            u[c] = __float_as_uint(vals[c]);
            eqm[c] = __ballot(u[c] == thr);
        }
        int r = base;
#pragma unroll
        for (int c = 0; c < 4; ++c) r += __popcll(eqm[c] & lt);
        float wout[4], mout[4];
#pragma unroll
        for (int c = 0; c < 4; ++c) {
            const bool iseq = (u[c] == thr);
            const bool sel = (u[c] > thr) || (iseq && r < need);
            r += iseq ? 1 : 0;
            wout[c] = sel ? vals[c] : 0.0f;
            mout[c] = sel ? 1.0f : 0.0f;
        }
#pragma unroll
        for (int c = 0; c < 4; ++c) base += __popcll(eqm[c]);
        w4o[m * 64 + lane] = make_float4(wout[0], wout[1], wout[2], wout[3]);
        m4o[m * 64 + lane] = make_float4(mout[0], mout[1], mout[2], mout[3]);
    }
}

extern "C" void kernel_launch(void* const* d_in, const int* in_sizes, int n_in,
                              void* d_out, int out_size, void* d_ws, size_t ws_size,
                              hipStream_t stream) {
    const float* hs = (const float*)d_in[0];   // [B,S,H] fp32
    const float* w  = (const float*)d_in[1];   // [H] fp32
    float* out      = (float*)d_out;           // [B*S] weights ++ [B*S] mask
    float* weights  = out;
    float* mask     = out + (size_t)BB * SS;
    float* scores   = mask;                    // stage scores in mask half; d_ws UNUSED

    const int tokens = BB * SS;                // 32768
    score_kernel<<<tokens / 8, 256, 0, stream>>>(hs, w, scores);
    select_kernel<<<BB, 64, 0, stream>>>(scores, out, mask);
}